// Round 8
// baseline (248.686 us; speedup 1.0000x reference)
//
#include <hip/hip_runtime.h>
#include <stdint.h>
#include <math.h>

#define EPSV   1e-5f
#define BATCH  4096
#define GDIM   4096
#define NF0    384     // folded level-0 output features (64 terms * 6)
#define NSPLIT 16      // GEMM split-K factor (16 -> 512 blocks = 2/CU overlap)

typedef __attribute__((ext_vector_type(8))) short bf16x8;
typedef __attribute__((ext_vector_type(4))) float f32x4;
typedef __attribute__((ext_vector_type(2))) float f32x2;
typedef __attribute__((ext_vector_type(4))) uint32_t u32x4;

__device__ __forceinline__ uint32_t pkbf(float x, float y) {
    uint32_t a = __float_as_uint(x) + 0x8000u;
    uint32_t b = __float_as_uint(y) + 0x8000u;
    return __builtin_amdgcn_perm(b, a, 0x07060302u);
}
__device__ __forceinline__ uint16_t f2bf(float f) {
    return (uint16_t)((__float_as_uint(f) + 0x8000u) >> 16);
}
__device__ __forceinline__ float blo(uint32_t v) {
    union { uint32_t u; float f; } x; x.u = v << 16; return x.f;
}
__device__ __forceinline__ float bhi(uint32_t v) {
    union { uint32_t u; float f; } x; x.u = v & 0xffff0000u; return x.f;
}
__device__ __forceinline__ void glds16(const uint16_t* g, short* l) {
    __builtin_amdgcn_global_load_lds(
        (const __attribute__((address_space(1))) void*)g,
        (__attribute__((address_space(3))) void*)l, 16, 0, 0);
}

// ---------------------------------------------------------------------------
// prep v2 (fold only): 1024 blocks.
// block 0 additionally zeroes stats (incl. stf) and precomputes bias0[384].
// ---------------------------------------------------------------------------
__global__ __launch_bounds__(256) void prep_kernel(
    const float* __restrict__ gene_W,
    const float* __restrict__ term_W, const float* __restrict__ term_b,
    const float* __restrict__ gene_b,
    uint16_t* __restrict__ m0, float* __restrict__ stats)
{
    const int tid = threadIdx.x;
    if (blockIdx.x == 0) {
        for (int j = tid; j < 1040; j += 256) stats[j] = 0.f;
        for (int f = tid; f < NF0; f += 256) {
            const int t = f / 6, h = f - t * 6;
            float b = term_b[f];
#pragma unroll
            for (int i = 0; i < 24; ++i)
                b += term_W[t * 144 + h * 24 + i] * gene_b[t * 24 + i];
            stats[1040 + f] = b;
        }
    }
    __shared__ float Wl[144];
    const int bid = blockIdx.x;               // 0..1023
    const int t = bid >> 4;                   // term 0..63
    const int g = ((bid & 15) << 8) + tid;    // gene 0..4095
    if (tid < 144) Wl[tid] = term_W[t * 144 + tid];
    __syncthreads();
    float gw[24];
#pragma unroll
    for (int i = 0; i < 24; ++i)
        gw[i] = gene_W[((size_t)t * 24 + i) * GDIM + g];
#pragma unroll
    for (int h = 0; h < 6; ++h) {
        float s = 0.f;
#pragma unroll
        for (int i = 0; i < 24; ++i) s += Wl[h * 24 + i] * gw[i];
        m0[((size_t)(t * 6 + h)) * GDIM + g] = f2bf(s);
    }
}

// ---------------------------------------------------------------------------
// gemm_wide: 128m x 384n x BK32 tile, split-K=16 -> 512 blocks = 2 blocks/CU.
// R7 A/B showed the GEMM is round-latency-bound (~2.7us/iter at 1 block/CU,
// invariant to bytes); 2 blocks/CU lets one block's MFMA cover the other's
// load round-trip. KC=256 -> 8 iters/block. LDS 56KB x2 = 112KB/CU fits;
// VGPR 76 -> 4 waves/SIMD = 2 blocks x 8 waves exactly.
// ---------------------------------------------------------------------------
__global__ __launch_bounds__(512) void gemm_wide(
    const float* __restrict__ A32, const uint16_t* __restrict__ Bw,
    uint16_t* __restrict__ P, int KC)
{
    const int N = NF0, K = GDIM;
    __shared__ short sA[128 * 32];
    __shared__ short sB[2][384 * 32];
    const int tid  = threadIdx.x;
    const int m0   = blockIdx.x * 128;
    const int kbase = blockIdx.y * KC;
    uint16_t* Cp = P + (size_t)blockIdx.y * ((size_t)BATCH * NF0);
    const int wave = tid >> 6, lane = tid & 63;
    const int wm   = (wave >> 2) * 64;     // wave row offset: 0 or 64
    const int wn   = (wave & 3) * 96;      // wave col offset: 0,96,192,288
    const int lm   = lane & 15, quad = lane >> 4;

    f32x4 acc[4][6];
#pragma unroll
    for (int i = 0; i < 4; ++i)
#pragma unroll
        for (int j = 0; j < 6; ++j) acc[i][j] = (f32x4){0.f, 0.f, 0.f, 0.f};

    const int r0  = tid >> 2;            // 0..127
    const int c0e = (tid & 3) << 3;      // 0,8,16,24
    const float*    gA = A32 + (size_t)(m0 + r0) * K + kbase + c0e;
    const uint16_t* gB = Bw  + (size_t)r0 * K + kbase + c0e;
    const size_t bskip = (size_t)128 * K;
    short* la = &sA[tid * 8];

    // ---- prologue: issue B(0) (3 glds) + A(0) (2 loads) ----
    glds16(gB,             &sB[0][tid * 8]);
    glds16(gB + bskip,     &sB[0][4096 + tid * 8]);
    glds16(gB + 2 * bskip, &sB[0][8192 + tid * 8]);
    f32x4 a0 = *(const f32x4*)(gA);
    f32x4 a1 = *(const f32x4*)(gA + 4);

    int cur = 0;
    for (int k0 = 0; k0 < KC - 32; k0 += 32) {
        const int kn = k0 + 32;
        glds16(gB + kn,             &sB[cur ^ 1][tid * 8]);
        glds16(gB + bskip + kn,     &sB[cur ^ 1][4096 + tid * 8]);
        glds16(gB + 2 * bskip + kn, &sB[cur ^ 1][8192 + tid * 8]);
        f32x4 n0v = *(const f32x4*)(gA + kn);
        f32x4 n1v = *(const f32x4*)(gA + kn + 4);
        // retire current tile (oldest 5); next tile (5 ops) stays in flight
        asm volatile("s_waitcnt vmcnt(5)" ::: "memory");
        u32x4 pa = (u32x4){pkbf(a0[0],a0[1]), pkbf(a0[2],a0[3]),
                           pkbf(a1[0],a1[1]), pkbf(a1[2],a1[3])};
        *(u32x4*)la = pa;
        asm volatile("s_waitcnt lgkmcnt(0)" ::: "memory");
        __builtin_amdgcn_s_barrier();
        bf16x8 af[4], bfr[6];
#pragma unroll
        for (int m = 0; m < 4; ++m)
            af[m]  = *(const bf16x8*)&sA[(wm + m * 16 + lm) * 32 + quad * 8];
#pragma unroll
        for (int n = 0; n < 6; ++n)
            bfr[n] = *(const bf16x8*)&sB[cur][(wn + n * 16 + lm) * 32 + quad * 8];
#pragma unroll
        for (int m = 0; m < 4; ++m)
#pragma unroll
            for (int n = 0; n < 6; ++n)
                acc[m][n] = __builtin_amdgcn_mfma_f32_16x16x32_bf16(
                    af[m], bfr[n], acc[m][n], 0, 0, 0);
        __builtin_amdgcn_s_barrier();   // protect sA + sB[cur^1] for next iter
        a0 = n0v; a1 = n1v;
        cur ^= 1;
    }
    // ---- tail ----
    asm volatile("s_waitcnt vmcnt(0)" ::: "memory");
    {
        u32x4 pa = (u32x4){pkbf(a0[0],a0[1]), pkbf(a0[2],a0[3]),
                           pkbf(a1[0],a1[1]), pkbf(a1[2],a1[3])};
        *(u32x4*)la = pa;
    }
    asm volatile("s_waitcnt lgkmcnt(0)" ::: "memory");
    __builtin_amdgcn_s_barrier();
    {
        bf16x8 af[4], bfr[6];
#pragma unroll
        for (int m = 0; m < 4; ++m)
            af[m]  = *(const bf16x8*)&sA[(wm + m * 16 + lm) * 32 + quad * 8];
#pragma unroll
        for (int n = 0; n < 6; ++n)
            bfr[n] = *(const bf16x8*)&sB[cur][(wn + n * 16 + lm) * 32 + quad * 8];
#pragma unroll
        for (int m = 0; m < 4; ++m)
#pragma unroll
            for (int n = 0; n < 6; ++n)
                acc[m][n] = __builtin_amdgcn_mfma_f32_16x16x32_bf16(
                    af[m], bfr[n], acc[m][n], 0, 0, 0);
    }
    // C/D layout: col = lane&15, row = quad*4 + reg
#pragma unroll
    for (int n = 0; n < 6; ++n) {
        const int col = wn + n * 16 + lm;
#pragma unroll
        for (int m = 0; m < 4; ++m) {
            const int row = m0 + wm + m * 16 + (quad << 2);
            uint16_t* cp = Cp + (size_t)row * N + col;
#pragma unroll
            for (int r = 0; r < 4; ++r) cp[(size_t)r * N] = f2bf(acc[m][n][r]);
        }
    }
}

// ---------------------------------------------------------------------------
// lzero v2: z0 = tanh(sum_z P[z] + bias0), dword-vectorized, 16 planes.
// ---------------------------------------------------------------------------
__global__ __launch_bounds__(256) void lzero_kernel(
    const uint16_t* __restrict__ P, const float* __restrict__ bias0,
    float* __restrict__ z0, float* __restrict__ st0)
{
    __shared__ float red[4 * 768];
    const int tid  = threadIdx.x;
    const int lane = tid & 63, wave = tid >> 6;
    const uint32_t* P32 = (const uint32_t*)P;

    const f32x2 b0 = ((const f32x2*)bias0)[lane];
    const f32x2 b1 = ((const f32x2*)(bias0 + 128))[lane];
    const f32x2 b2 = ((const f32x2*)(bias0 + 256))[lane];

    float s[6], q[6];
#pragma unroll
    for (int k = 0; k < 6; ++k) { s[k] = 0.f; q[k] = 0.f; }

    const int rbase = blockIdx.x * 8 + wave * 2;
    for (int rl = 0; rl < 2; ++rl) {
        const int r = rbase + rl;
        float a0 = b0[0], a1 = b0[1], a2 = b1[0], a3 = b1[1], a4 = b2[0], a5 = b2[1];
        const uint32_t* pr = P32 + (size_t)r * 192 + lane;
#pragma unroll
        for (int z = 0; z < NSPLIT; ++z) {
            const uint32_t* p = pr + (size_t)z * ((size_t)BATCH * 192);
            uint32_t u0 = p[0], u1 = p[64], u2 = p[128];
            a0 += blo(u0); a1 += bhi(u0);
            a2 += blo(u1); a3 += bhi(u1);
            a4 += blo(u2); a5 += bhi(u2);
        }
        float z0v = tanhf(a0), z1v = tanhf(a1), z2v = tanhf(a2);
        float z3v = tanhf(a3), z4v = tanhf(a4), z5v = tanhf(a5);
        f32x2* zr = (f32x2*)(z0 + (size_t)r * NF0);
        zr[lane]       = (f32x2){z0v, z1v};
        zr[64 + lane]  = (f32x2){z2v, z3v};
        zr[128 + lane] = (f32x2){z4v, z5v};
        s[0] += z0v; q[0] += z0v * z0v;
        s[1] += z1v; q[1] += z1v * z1v;
        s[2] += z2v; q[2] += z2v * z2v;
        s[3] += z3v; q[3] += z3v * z3v;
        s[4] += z4v; q[4] += z4v * z4v;
        s[5] += z5v; q[5] += z5v * z5v;
    }
    float* rw = &red[wave * 768 + lane * 12];
#pragma unroll
    for (int k = 0; k < 6; ++k) { rw[k] = s[k]; rw[6 + k] = q[k]; }
    __syncthreads();
    for (int idx = tid; idx < 768; idx += 256) {
        float v = red[idx] + red[768 + idx] + red[1536 + idx] + red[2304 + idx];
        const int l = idx / 12, k = idx - l * 12;
        const int k6 = k % 6;
        const int f = (k6 >> 1) * 128 + 2 * l + (k6 & 1);
        atomicAdd(&st0[(k >= 6 ? NF0 : 0) + f], v);
    }
}

// ---------------------------------------------------------------------------
// Level kernel (R4-proven).
// ---------------------------------------------------------------------------
template <int N, int ROWS, int OFF, int PREV_OFF>
__global__ __launch_bounds__(256) void level_kernel(
    const float* __restrict__ in, float* __restrict__ z_out,
    const float* __restrict__ stats_prev, float* __restrict__ stats_out,
    const float* __restrict__ term_W, const float* __restrict__ term_b,
    const float* __restrict__ bn_gamma, const float* __restrict__ bn_beta,
    const float* __restrict__ aux1_W, const float* __restrict__ aux1_b,
    const float* __restrict__ aux2_W, const float* __restrict__ aux2_b,
    float* __restrict__ out)
{
    constexpr int IN_W  = 24 * N;
    constexpr int NFv   = 6 * N;
    constexpr int NG    = 256 / N;
    constexpr int ITERS = (ROWS * N) / 256;
    constexpr int NPREV = 4 * N;

    __shared__ float Wl[144 * N];
    __shared__ float tbl[6 * N];
    __shared__ float aA[IN_W];
    __shared__ float aC[IN_W];
    __shared__ float a1wL[6 * NPREV];
    __shared__ float a1bL[NPREV], a2wL[NPREV], a2bL[NPREV];
    __shared__ float ps[NG * NFv], pq[NG * NFv];

    const int tid = threadIdx.x;
    for (int idx = tid; idx < 144 * N; idx += 256) {
        int t = idx / 144, fh = idx - t * 144;
        Wl[fh * N + t] = term_W[(OFF + t) * 144 + fh];
    }
    for (int idx = tid; idx < 6 * N; idx += 256) {
        int t = idx / 6, h = idx - t * 6;
        tbl[h * N + t] = term_b[(OFF + t) * 6 + h];
    }
    {
        const float invB = 1.0f / BATCH;
        for (int j = tid; j < IN_W; j += 256) {
            float s = stats_prev[j], q = stats_prev[IN_W + j];
            float mu = s * invB;
            float var = q * invB - mu * mu;
            float rstd = rsqrtf(var + EPSV);
            float a = rstd * bn_gamma[PREV_OFF * 6 + j];
            int t = j / 24, i = j - t * 24;
            aA[i * N + t] = a;
            aC[i * N + t] = bn_beta[PREV_OFF * 6 + j] - mu * a;
        }
        for (int idx = tid; idx < 6 * NPREV; idx += 256) {
            int t = idx / 6, h = idx - t * 6;
            a1wL[h * NPREV + t] = aux1_W[(PREV_OFF + t) * 6 + h];
        }
        for (int t = tid; t < NPREV; t += 256) {
            a1bL[t] = aux1_b[PREV_OFF + t];
            a2wL[t] = aux2_W[PREV_OFF + t];
            a2bL[t] = aux2_b[PREV_OFF + t];
        }
    }
    __syncthreads();

    const int term = tid & (N - 1);
    const int grp  = tid / N;
    float s6[6], q6[6];
#pragma unroll
    for (int h = 0; h < 6; ++h) { s6[h] = 0.f; q6[h] = 0.f; }

    for (int it = 0; it < ITERS; ++it) {
        const int r = blockIdx.x * ROWS + it * NG + grp;
        const float* inrow = in + (size_t)r * IN_W + term * 24;
        float hv[24];
#pragma unroll
        for (int i4 = 0; i4 < 6; ++i4) {
            f32x4 v = *(const f32x4*)(inrow + 4 * i4);
            hv[4*i4+0] = v[0]; hv[4*i4+1] = v[1];
            hv[4*i4+2] = v[2]; hv[4*i4+3] = v[3];
        }
#pragma unroll
        for (int i = 0; i < 24; ++i)
            hv[i] = hv[i] * aA[i * N + term] + aC[i * N + term];
#pragma unroll
        for (int s = 0; s < 4; ++s) {
            const int tp = term * 4 + s;
            float acc = a1bL[tp];
#pragma unroll
            for (int h2 = 0; h2 < 6; ++h2) acc += hv[s * 6 + h2] * a1wL[h2 * NPREV + tp];
            float a1 = tanhf(acc);
            out[(size_t)r * 86 + PREV_OFF + tp] = a1 * a2wL[tp] + a2bL[tp];
        }
        float za[6];
#pragma unroll
        for (int h = 0; h < 6; ++h) za[h] = tbl[h * N + term];
#pragma unroll
        for (int i = 0; i < 24; ++i) {
            const float x = hv[i];
#pragma unroll
            for (int h = 0; h < 6; ++h) za[h] += x * Wl[(h * 24 + i) * N + term];
        }
        float* zr = z_out + (size_t)r * NFv + term * 6;
#pragma unroll
        for (int h = 0; h < 6; ++h) {
            float z = tanhf(za[h]);
            zr[h] = z;
            s6[h] += z;
            q6[h] += z * z;
        }
    }
#pragma unroll
    for (int h = 0; h < 6; ++h) {
        ps[grp * NFv + term * 6 + h] = s6[h];
        pq[grp * NFv + term * 6 + h] = q6[h];
    }
    __syncthreads();
    for (int f = tid; f < NFv; f += 256) {
        float s = 0.f, q = 0.f;
        for (int g2 = 0; g2 < NG; ++g2) { s += ps[g2 * NFv + f]; q += pq[g2 * NFv + f]; }
        atomicAdd(&stats_out[f], s);
        atomicAdd(&stats_out[NFv + f], q);
    }
}

// ---------------------------------------------------------------------------
// final_p1: 16 blocks x 256 thr, 1 row/thread.
// ---------------------------------------------------------------------------
__global__ __launch_bounds__(256) void final_p1(
    const float* __restrict__ z3, const float* __restrict__ st3,
    const float* __restrict__ bn_gamma, const float* __restrict__ bn_beta,
    const float* __restrict__ aux1_W, const float* __restrict__ aux1_b,
    const float* __restrict__ aux2_W, const float* __restrict__ aux2_b,
    const float* __restrict__ final_W, const float* __restrict__ final_b,
    float* __restrict__ fbuf, float* __restrict__ stf,
    float* __restrict__ out)
{
    __shared__ float wred[4][12];
    const int tid = threadIdx.x;
    const int r = blockIdx.x * 256 + tid;
    const float invB = 1.0f / BATCH;
    float a[6], c[6];
#pragma unroll
    for (int j = 0; j < 6; ++j) {
        float s = st3[j], q = st3[6 + j];
        float mu = s * invB, var = q * invB - mu * mu;
        float rstd = rsqrtf(var + EPSV);
        a[j] = rstd * bn_gamma[504 + j];
        c[j] = bn_beta[504 + j] - mu * a[j];
    }
    float h[6];
    {
        f32x2 z01 = *(const f32x2*)(z3 + (size_t)r * 6);
        f32x2 z23 = *(const f32x2*)(z3 + (size_t)r * 6 + 2);
        f32x2 z45 = *(const f32x2*)(z3 + (size_t)r * 6 + 4);
        h[0] = z01[0] * a[0] + c[0]; h[1] = z01[1] * a[1] + c[1];
        h[2] = z23[0] * a[2] + c[2]; h[3] = z23[1] * a[3] + c[3];
        h[4] = z45[0] * a[4] + c[4]; h[5] = z45[1] * a[5] + c[5];
    }
    float acc = aux1_b[84];
#pragma unroll
    for (int j = 0; j < 6; ++j) acc += h[j] * aux1_W[504 + j];
    out[(size_t)r * 86 + 84] = tanhf(acc) * aux2_W[84] + aux2_b[84];

    float f[6], s6[6], q6[6];
#pragma unroll
    for (int j = 0; j < 6; ++j) {
        float s = final_b[j];
#pragma unroll
        for (int k = 0; k < 6; ++k) s += h[k] * final_W[j * 6 + k];
        f[j] = tanhf(s);
        s6[j] = f[j]; q6[j] = f[j] * f[j];
    }
    {
        f32x2* fr = (f32x2*)(fbuf + (size_t)r * 6);
        fr[0] = (f32x2){f[0], f[1]};
        fr[1] = (f32x2){f[2], f[3]};
        fr[2] = (f32x2){f[4], f[5]};
    }
#pragma unroll
    for (int off = 32; off >= 1; off >>= 1) {
#pragma unroll
        for (int j = 0; j < 6; ++j) {
            s6[j] += __shfl_xor(s6[j], off, 64);
            q6[j] += __shfl_xor(q6[j], off, 64);
        }
    }
    const int wv = tid >> 6, ln = tid & 63;
    if (ln == 0) {
#pragma unroll
        for (int j = 0; j < 6; ++j) { wred[wv][j] = s6[j]; wred[wv][6 + j] = q6[j]; }
    }
    __syncthreads();
    if (tid < 12) {
        float s = wred[0][tid] + wred[1][tid] + wred[2][tid] + wred[3][tid];
        atomicAdd(&stf[tid], s);
    }
}

// ---------------------------------------------------------------------------
// final_p2: 16 blocks x 256 thr, 1 row/thread.
// ---------------------------------------------------------------------------
__global__ __launch_bounds__(256) void final_p2(
    const float* __restrict__ fbuf, const float* __restrict__ stf,
    const float* __restrict__ fbn_gamma, const float* __restrict__ fbn_beta,
    const float* __restrict__ faux_W, const float* __restrict__ faux_b,
    const float* __restrict__ fout_W, const float* __restrict__ fout_b,
    float* __restrict__ out)
{
    const int tid = threadIdx.x;
    const int r = blockIdx.x * 256 + tid;
    const float invB = 1.0f / BATCH;
    float av[6], cv[6];
#pragma unroll
    for (int j = 0; j < 6; ++j) {
        float mu = stf[j] * invB, var = stf[6 + j] * invB - mu * mu;
        float rstd = rsqrtf(var + EPSV);
        av[j] = rstd * fbn_gamma[j];
        cv[j] = fbn_beta[j] - mu * av[j];
    }
    float f[6];
    {
        f32x2 f01 = *(const f32x2*)(fbuf + (size_t)r * 6);
        f32x2 f23 = *(const f32x2*)(fbuf + (size_t)r * 6 + 2);
        f32x2 f45 = *(const f32x2*)(fbuf + (size_t)r * 6 + 4);
        f[0] = f01[0]; f[1] = f01[1]; f[2] = f23[0];
        f[3] = f23[1]; f[4] = f45[0]; f[5] = f45[1];
    }
    float acc2 = faux_b[0];
#pragma unroll
    for (int j = 0; j < 6; ++j) acc2 += (f[j] * av[j] + cv[j]) * faux_W[j];
    float fa  = tanhf(acc2);
    float pre = fa * fout_W[0] + fout_b[0];
    out[(size_t)r * 86 + 85] = 1.0f / (1.0f + expf(-pre));
}

// ---------------------------------------------------------------------------
extern "C" void kernel_launch(void* const* d_in, const int* in_sizes, int n_in,
                              void* d_out, int out_size, void* d_ws, size_t ws_size,
                              hipStream_t stream)
{
    const float* x      = (const float*)d_in[0];
    const float* gene_W = (const float*)d_in[1];
    const float* gene_b = (const float*)d_in[2];
    const float* term_W = (const float*)d_in[3];
    const float* term_b = (const float*)d_in[4];
    const float* bn_g   = (const float*)d_in[5];
    const float* bn_b   = (const float*)d_in[6];
    const float* a1W    = (const float*)d_in[7];
    const float* a1b    = (const float*)d_in[8];
    const float* a2W    = (const float*)d_in[9];
    const float* a2b    = (const float*)d_in[10];
    const float* fW     = (const float*)d_in[11];
    const float* fb     = (const float*)d_in[12];
    const float* fbn_g  = (const float*)d_in[13];
    const float* fbn_b  = (const float*)d_in[14];
    const float* fxW    = (const float*)d_in[15];
    const float* fxb    = (const float*)d_in[16];
    const float* foW    = (const float*)d_in[17];
    const float* fob    = (const float*)d_in[18];
    float* out = (float*)d_out;

    const size_t M0B = (size_t)NF0 * GDIM * 2;            // 3,145,728
    const size_t PB  = (size_t)NSPLIT * BATCH * NF0 * 2;  // 50,331,648
    const size_t Z0B = (size_t)BATCH * NF0 * 4;           // 6,291,456

    char* ws = (char*)d_ws;
    uint16_t* m0b  = (uint16_t*)ws;
    uint16_t* pbuf = (uint16_t*)(ws + M0B);
    float*    z0   = (float*)(ws + M0B + PB);
    float*    z1   = (float*)(ws + M0B + PB + Z0B);
    float*    z2   = (float*)(ws + M0B + PB + Z0B + 1572864);
    float*    z3   = (float*)(ws + M0B + PB + Z0B + 1572864 + 393216);
    float*    stats = (float*)(ws + M0B + PB + Z0B + 1572864 + 393216 + 98304);
    float* st0 = stats;          // 384+384
    float* st1 = stats + 768;    // 96+96
    float* st2 = stats + 960;    // 24+24
    float* st3 = stats + 1008;   // 6+6
    float* stf = stats + 1020;   // 6+6 (final-BN stats; zeroed by prep)
    float* bias0 = stats + 1040; // 384 (written by prep block 0)
    float* fbuf  = stats + 2048; // 4096*6 f32

    prep_kernel<<<1024, 256, 0, stream>>>(gene_W, term_W, term_b, gene_b,
                                          m0b, stats);
    gemm_wide<<<dim3(32, NSPLIT), 512, 0, stream>>>(x, m0b, pbuf, GDIM / NSPLIT);
    lzero_kernel<<<512, 256, 0, stream>>>(pbuf, bias0, z0, st0);
    level_kernel<16, 16, 64, 0><<<256, 256, 0, stream>>>(
        z0, z1, st0, st1, term_W, term_b, bn_g, bn_b, a1W, a1b, a2W, a2b, out);
    level_kernel<4, 64, 80, 64><<<64, 256, 0, stream>>>(
        z1, z2, st1, st2, term_W, term_b, bn_g, bn_b, a1W, a1b, a2W, a2b, out);
    level_kernel<1, 256, 84, 80><<<16, 256, 0, stream>>>(
        z2, z3, st2, st3, term_W, term_b, bn_g, bn_b, a1W, a1b, a2W, a2b, out);
    final_p1<<<16, 256, 0, stream>>>(
        z3, st3, bn_g, bn_b, a1W, a1b, a2W, a2b, fW, fb, fbuf, stf, out);
    final_p2<<<16, 256, 0, stream>>>(
        fbuf, stf, fbn_g, fbn_b, fxW, fxb, foW, fob, out);
}

// Round 9
// 235.320 us; speedup vs baseline: 1.0568x; 1.0568x over previous
//
#include <hip/hip_runtime.h>
#include <stdint.h>
#include <math.h>

#define EPSV   1e-5f
#define BATCH  4096
#define GDIM   4096
#define NF0    384     // folded level-0 output features (64 terms * 6)
#define NSPLIT 8       // GEMM split-K factor

typedef __attribute__((ext_vector_type(8))) short bf16x8;
typedef __attribute__((ext_vector_type(4))) float f32x4;
typedef __attribute__((ext_vector_type(2))) float f32x2;
typedef __attribute__((ext_vector_type(4))) uint32_t u32x4;

__device__ __forceinline__ uint32_t pkbf(float x, float y) {
    uint32_t a = __float_as_uint(x) + 0x8000u;
    uint32_t b = __float_as_uint(y) + 0x8000u;
    return __builtin_amdgcn_perm(b, a, 0x07060302u);
}
__device__ __forceinline__ uint16_t f2bf(float f) {
    return (uint16_t)((__float_as_uint(f) + 0x8000u) >> 16);
}
__device__ __forceinline__ float blo(uint32_t v) {
    union { uint32_t u; float f; } x; x.u = v << 16; return x.f;
}
__device__ __forceinline__ float bhi(uint32_t v) {
    union { uint32_t u; float f; } x; x.u = v & 0xffff0000u; return x.f;
}
__device__ __forceinline__ void glds16(const uint16_t* g, short* l) {
    __builtin_amdgcn_global_load_lds(
        (const __attribute__((address_space(1))) void*)g,
        (__attribute__((address_space(3))) void*)l, 16, 0, 0);
}

// ---------------------------------------------------------------------------
// prep v2 (fold only): 1024 blocks.
// block 0 additionally zeroes stats (incl. stf) and precomputes bias0[384].
// ---------------------------------------------------------------------------
__global__ __launch_bounds__(256) void prep_kernel(
    const float* __restrict__ gene_W,
    const float* __restrict__ term_W, const float* __restrict__ term_b,
    const float* __restrict__ gene_b,
    uint16_t* __restrict__ m0, float* __restrict__ stats)
{
    const int tid = threadIdx.x;
    if (blockIdx.x == 0) {
        for (int j = tid; j < 1040; j += 256) stats[j] = 0.f;
        for (int f = tid; f < NF0; f += 256) {
            const int t = f / 6, h = f - t * 6;
            float b = term_b[f];
#pragma unroll
            for (int i = 0; i < 24; ++i)
                b += term_W[t * 144 + h * 24 + i] * gene_b[t * 24 + i];
            stats[1040 + f] = b;
        }
    }
    __shared__ float Wl[144];
    const int bid = blockIdx.x;               // 0..1023
    const int t = bid >> 4;                   // term 0..63
    const int g = ((bid & 15) << 8) + tid;    // gene 0..4095
    if (tid < 144) Wl[tid] = term_W[t * 144 + tid];
    __syncthreads();
    float gw[24];
#pragma unroll
    for (int i = 0; i < 24; ++i)
        gw[i] = gene_W[((size_t)t * 24 + i) * GDIM + g];
#pragma unroll
    for (int h = 0; h < 6; ++h) {
        float s = 0.f;
#pragma unroll
        for (int i = 0; i < 24; ++i) s += Wl[h * 24 + i] * gw[i];
        m0[((size_t)(t * 6 + h)) * GDIM + g] = f2bf(s);
    }
}

// ---------------------------------------------------------------------------
// gemm_wide BK=64: 128m x 384n x 64k rounds, NSPLIT=8 -> KC=512 -> 8 rounds.
// R6/R7/R8 A/B isolated the invariant: ~2.7us per K-round per CU, independent
// of bytes/round (24KB vs 40KB) and blocks/CU (1/2/3). So: halve the rounds.
// Per round: 6 B-glds16 + 4 A-f32x4 loads; counted vmcnt(10); 2 kk-subtiles
// x 24 MFMA. LDS 112KB -> 1 block/CU (co-residency proven worthless, R8).
// Same barrier skeleton + K-order as R7 -> P bit-identical.
// ---------------------------------------------------------------------------
__global__ __launch_bounds__(512) void gemm_wide(
    const float* __restrict__ A32, const uint16_t* __restrict__ Bw,
    uint16_t* __restrict__ P, int KC)
{
    const int N = NF0, K = GDIM;
    __shared__ short sA[128 * 64];        // 16 KB
    __shared__ short sB[2][384 * 64];     // 2 x 48 KB
    const int tid  = threadIdx.x;
    const int m0   = blockIdx.x * 128;
    const int kbase = blockIdx.y * KC;
    uint16_t* Cp = P + (size_t)blockIdx.y * ((size_t)BATCH * NF0);
    const int wave = tid >> 6, lane = tid & 63;
    const int wm   = (wave >> 2) * 64;     // wave row offset: 0 or 64
    const int wn   = (wave & 3) * 96;      // wave col offset: 0,96,192,288
    const int lm   = lane & 15, quad = lane >> 4;

    f32x4 acc[4][6];
#pragma unroll
    for (int i = 0; i < 4; ++i)
#pragma unroll
        for (int j = 0; j < 6; ++j) acc[i][j] = (f32x4){0.f, 0.f, 0.f, 0.f};

    // A: row rA = tid>>2 (0..127), k-cols cA..cA+15 (cA = (tid&3)*16)
    const int rA = tid >> 2, cA = (tid & 3) << 4;
    const float* gA = A32 + (size_t)(m0 + rA) * K + kbase + cA;
    short* la = &sA[rA * 64 + cA];        // 16 bf16 = 32 B, 32B-aligned
    // B: row rB = tid>>3 (0..63), k-cols cB..cB+7 (cB = (tid&7)*8)
    // lds linear offset (tid*8 shorts) == rB*64 + cB  (row-major stride 64)
    const int rB = tid >> 3, cB = (tid & 7) << 3;
    const uint16_t* gB = Bw + (size_t)rB * K + kbase + cB;
    const size_t bskip = (size_t)64 * K;  // 64 rows per glds batch

    // ---- prologue: B(0) 6 glds + A(0) 4 f32x4 ----
#pragma unroll
    for (int j = 0; j < 6; ++j)
        glds16(gB + j * bskip, &sB[0][j * 4096 + tid * 8]);
    f32x4 a0 = *(const f32x4*)(gA);
    f32x4 a1 = *(const f32x4*)(gA + 4);
    f32x4 a2 = *(const f32x4*)(gA + 8);
    f32x4 a3 = *(const f32x4*)(gA + 12);

    int cur = 0;
    for (int k0 = 0; k0 < KC - 64; k0 += 64) {
        const int kn = k0 + 64;
#pragma unroll
        for (int j = 0; j < 6; ++j)
            glds16(gB + j * bskip + kn, &sB[cur ^ 1][j * 4096 + tid * 8]);
        f32x4 n0v = *(const f32x4*)(gA + kn);
        f32x4 n1v = *(const f32x4*)(gA + kn + 4);
        f32x4 n2v = *(const f32x4*)(gA + kn + 8);
        f32x4 n3v = *(const f32x4*)(gA + kn + 12);
        // retire current tile (oldest 10); next tile (10 ops) stays in flight
        asm volatile("s_waitcnt vmcnt(10)" ::: "memory");
        u32x4 pa0 = (u32x4){pkbf(a0[0],a0[1]), pkbf(a0[2],a0[3]),
                            pkbf(a1[0],a1[1]), pkbf(a1[2],a1[3])};
        u32x4 pa1 = (u32x4){pkbf(a2[0],a2[1]), pkbf(a2[2],a2[3]),
                            pkbf(a3[0],a3[1]), pkbf(a3[2],a3[3])};
        *(u32x4*)la = pa0;
        *(u32x4*)(la + 8) = pa1;
        asm volatile("s_waitcnt lgkmcnt(0)" ::: "memory");
        __builtin_amdgcn_s_barrier();
#pragma unroll
        for (int kk = 0; kk < 2; ++kk) {
            bf16x8 af[4], bfr[6];
#pragma unroll
            for (int m = 0; m < 4; ++m)
                af[m]  = *(const bf16x8*)&sA[(wm + m * 16 + lm) * 64 + kk * 32 + quad * 8];
#pragma unroll
            for (int n = 0; n < 6; ++n)
                bfr[n] = *(const bf16x8*)&sB[cur][(wn + n * 16 + lm) * 64 + kk * 32 + quad * 8];
#pragma unroll
            for (int m = 0; m < 4; ++m)
#pragma unroll
                for (int n = 0; n < 6; ++n)
                    acc[m][n] = __builtin_amdgcn_mfma_f32_16x16x32_bf16(
                        af[m], bfr[n], acc[m][n], 0, 0, 0);
        }
        __builtin_amdgcn_s_barrier();   // protect sA + sB[cur^1] for next iter
        a0 = n0v; a1 = n1v; a2 = n2v; a3 = n3v;
        cur ^= 1;
    }
    // ---- tail ----
    asm volatile("s_waitcnt vmcnt(0)" ::: "memory");
    {
        u32x4 pa0 = (u32x4){pkbf(a0[0],a0[1]), pkbf(a0[2],a0[3]),
                            pkbf(a1[0],a1[1]), pkbf(a1[2],a1[3])};
        u32x4 pa1 = (u32x4){pkbf(a2[0],a2[1]), pkbf(a2[2],a2[3]),
                            pkbf(a3[0],a3[1]), pkbf(a3[2],a3[3])};
        *(u32x4*)la = pa0;
        *(u32x4*)(la + 8) = pa1;
    }
    asm volatile("s_waitcnt lgkmcnt(0)" ::: "memory");
    __builtin_amdgcn_s_barrier();
#pragma unroll
    for (int kk = 0; kk < 2; ++kk) {
        bf16x8 af[4], bfr[6];
#pragma unroll
        for (int m = 0; m < 4; ++m)
            af[m]  = *(const bf16x8*)&sA[(wm + m * 16 + lm) * 64 + kk * 32 + quad * 8];
#pragma unroll
        for (int n = 0; n < 6; ++n)
            bfr[n] = *(const bf16x8*)&sB[cur][(wn + n * 16 + lm) * 64 + kk * 32 + quad * 8];
#pragma unroll
        for (int m = 0; m < 4; ++m)
#pragma unroll
            for (int n = 0; n < 6; ++n)
                acc[m][n] = __builtin_amdgcn_mfma_f32_16x16x32_bf16(
                    af[m], bfr[n], acc[m][n], 0, 0, 0);
    }
    // C/D layout: col = lane&15, row = quad*4 + reg
#pragma unroll
    for (int n = 0; n < 6; ++n) {
        const int col = wn + n * 16 + lm;
#pragma unroll
        for (int m = 0; m < 4; ++m) {
            const int row = m0 + wm + m * 16 + (quad << 2);
            uint16_t* cp = Cp + (size_t)row * N + col;
#pragma unroll
            for (int r = 0; r < 4; ++r) cp[(size_t)r * N] = f2bf(acc[m][n][r]);
        }
    }
}

// ---------------------------------------------------------------------------
// lzero v2: z0 = tanh(sum_z P[z] + bias0), dword-vectorized, 8 planes.
// ---------------------------------------------------------------------------
__global__ __launch_bounds__(256) void lzero_kernel(
    const uint16_t* __restrict__ P, const float* __restrict__ bias0,
    float* __restrict__ z0, float* __restrict__ st0)
{
    __shared__ float red[4 * 768];
    const int tid  = threadIdx.x;
    const int lane = tid & 63, wave = tid >> 6;
    const uint32_t* P32 = (const uint32_t*)P;

    const f32x2 b0 = ((const f32x2*)bias0)[lane];
    const f32x2 b1 = ((const f32x2*)(bias0 + 128))[lane];
    const f32x2 b2 = ((const f32x2*)(bias0 + 256))[lane];

    float s[6], q[6];
#pragma unroll
    for (int k = 0; k < 6; ++k) { s[k] = 0.f; q[k] = 0.f; }

    const int rbase = blockIdx.x * 8 + wave * 2;
    for (int rl = 0; rl < 2; ++rl) {
        const int r = rbase + rl;
        float a0 = b0[0], a1 = b0[1], a2 = b1[0], a3 = b1[1], a4 = b2[0], a5 = b2[1];
        const uint32_t* pr = P32 + (size_t)r * 192 + lane;
#pragma unroll
        for (int z = 0; z < NSPLIT; ++z) {
            const uint32_t* p = pr + (size_t)z * ((size_t)BATCH * 192);
            uint32_t u0 = p[0], u1 = p[64], u2 = p[128];
            a0 += blo(u0); a1 += bhi(u0);
            a2 += blo(u1); a3 += bhi(u1);
            a4 += blo(u2); a5 += bhi(u2);
        }
        float z0v = tanhf(a0), z1v = tanhf(a1), z2v = tanhf(a2);
        float z3v = tanhf(a3), z4v = tanhf(a4), z5v = tanhf(a5);
        f32x2* zr = (f32x2*)(z0 + (size_t)r * NF0);
        zr[lane]       = (f32x2){z0v, z1v};
        zr[64 + lane]  = (f32x2){z2v, z3v};
        zr[128 + lane] = (f32x2){z4v, z5v};
        s[0] += z0v; q[0] += z0v * z0v;
        s[1] += z1v; q[1] += z1v * z1v;
        s[2] += z2v; q[2] += z2v * z2v;
        s[3] += z3v; q[3] += z3v * z3v;
        s[4] += z4v; q[4] += z4v * z4v;
        s[5] += z5v; q[5] += z5v * z5v;
    }
    float* rw = &red[wave * 768 + lane * 12];
#pragma unroll
    for (int k = 0; k < 6; ++k) { rw[k] = s[k]; rw[6 + k] = q[k]; }
    __syncthreads();
    for (int idx = tid; idx < 768; idx += 256) {
        float v = red[idx] + red[768 + idx] + red[1536 + idx] + red[2304 + idx];
        const int l = idx / 12, k = idx - l * 12;
        const int k6 = k % 6;
        const int f = (k6 >> 1) * 128 + 2 * l + (k6 & 1);
        atomicAdd(&st0[(k >= 6 ? NF0 : 0) + f], v);
    }
}

// ---------------------------------------------------------------------------
// Level kernel (R4-proven).
// ---------------------------------------------------------------------------
template <int N, int ROWS, int OFF, int PREV_OFF>
__global__ __launch_bounds__(256) void level_kernel(
    const float* __restrict__ in, float* __restrict__ z_out,
    const float* __restrict__ stats_prev, float* __restrict__ stats_out,
    const float* __restrict__ term_W, const float* __restrict__ term_b,
    const float* __restrict__ bn_gamma, const float* __restrict__ bn_beta,
    const float* __restrict__ aux1_W, const float* __restrict__ aux1_b,
    const float* __restrict__ aux2_W, const float* __restrict__ aux2_b,
    float* __restrict__ out)
{
    constexpr int IN_W  = 24 * N;
    constexpr int NFv   = 6 * N;
    constexpr int NG    = 256 / N;
    constexpr int ITERS = (ROWS * N) / 256;
    constexpr int NPREV = 4 * N;

    __shared__ float Wl[144 * N];
    __shared__ float tbl[6 * N];
    __shared__ float aA[IN_W];
    __shared__ float aC[IN_W];
    __shared__ float a1wL[6 * NPREV];
    __shared__ float a1bL[NPREV], a2wL[NPREV], a2bL[NPREV];
    __shared__ float ps[NG * NFv], pq[NG * NFv];

    const int tid = threadIdx.x;
    for (int idx = tid; idx < 144 * N; idx += 256) {
        int t = idx / 144, fh = idx - t * 144;
        Wl[fh * N + t] = term_W[(OFF + t) * 144 + fh];
    }
    for (int idx = tid; idx < 6 * N; idx += 256) {
        int t = idx / 6, h = idx - t * 6;
        tbl[h * N + t] = term_b[(OFF + t) * 6 + h];
    }
    {
        const float invB = 1.0f / BATCH;
        for (int j = tid; j < IN_W; j += 256) {
            float s = stats_prev[j], q = stats_prev[IN_W + j];
            float mu = s * invB;
            float var = q * invB - mu * mu;
            float rstd = rsqrtf(var + EPSV);
            float a = rstd * bn_gamma[PREV_OFF * 6 + j];
            int t = j / 24, i = j - t * 24;
            aA[i * N + t] = a;
            aC[i * N + t] = bn_beta[PREV_OFF * 6 + j] - mu * a;
        }
        for (int idx = tid; idx < 6 * NPREV; idx += 256) {
            int t = idx / 6, h = idx - t * 6;
            a1wL[h * NPREV + t] = aux1_W[(PREV_OFF + t) * 6 + h];
        }
        for (int t = tid; t < NPREV; t += 256) {
            a1bL[t] = aux1_b[PREV_OFF + t];
            a2wL[t] = aux2_W[PREV_OFF + t];
            a2bL[t] = aux2_b[PREV_OFF + t];
        }
    }
    __syncthreads();

    const int term = tid & (N - 1);
    const int grp  = tid / N;
    float s6[6], q6[6];
#pragma unroll
    for (int h = 0; h < 6; ++h) { s6[h] = 0.f; q6[h] = 0.f; }

    for (int it = 0; it < ITERS; ++it) {
        const int r = blockIdx.x * ROWS + it * NG + grp;
        const float* inrow = in + (size_t)r * IN_W + term * 24;
        float hv[24];
#pragma unroll
        for (int i4 = 0; i4 < 6; ++i4) {
            f32x4 v = *(const f32x4*)(inrow + 4 * i4);
            hv[4*i4+0] = v[0]; hv[4*i4+1] = v[1];
            hv[4*i4+2] = v[2]; hv[4*i4+3] = v[3];
        }
#pragma unroll
        for (int i = 0; i < 24; ++i)
            hv[i] = hv[i] * aA[i * N + term] + aC[i * N + term];
#pragma unroll
        for (int s = 0; s < 4; ++s) {
            const int tp = term * 4 + s;
            float acc = a1bL[tp];
#pragma unroll
            for (int h2 = 0; h2 < 6; ++h2) acc += hv[s * 6 + h2] * a1wL[h2 * NPREV + tp];
            float a1 = tanhf(acc);
            out[(size_t)r * 86 + PREV_OFF + tp] = a1 * a2wL[tp] + a2bL[tp];
        }
        float za[6];
#pragma unroll
        for (int h = 0; h < 6; ++h) za[h] = tbl[h * N + term];
#pragma unroll
        for (int i = 0; i < 24; ++i) {
            const float x = hv[i];
#pragma unroll
            for (int h = 0; h < 6; ++h) za[h] += x * Wl[(h * 24 + i) * N + term];
        }
        float* zr = z_out + (size_t)r * NFv + term * 6;
#pragma unroll
        for (int h = 0; h < 6; ++h) {
            float z = tanhf(za[h]);
            zr[h] = z;
            s6[h] += z;
            q6[h] += z * z;
        }
    }
#pragma unroll
    for (int h = 0; h < 6; ++h) {
        ps[grp * NFv + term * 6 + h] = s6[h];
        pq[grp * NFv + term * 6 + h] = q6[h];
    }
    __syncthreads();
    for (int f = tid; f < NFv; f += 256) {
        float s = 0.f, q = 0.f;
        for (int g2 = 0; g2 < NG; ++g2) { s += ps[g2 * NFv + f]; q += pq[g2 * NFv + f]; }
        atomicAdd(&stats_out[f], s);
        atomicAdd(&stats_out[NFv + f], q);
    }
}

// ---------------------------------------------------------------------------
// final_p1: 16 blocks x 256 thr, 1 row/thread.
// ---------------------------------------------------------------------------
__global__ __launch_bounds__(256) void final_p1(
    const float* __restrict__ z3, const float* __restrict__ st3,
    const float* __restrict__ bn_gamma, const float* __restrict__ bn_beta,
    const float* __restrict__ aux1_W, const float* __restrict__ aux1_b,
    const float* __restrict__ aux2_W, const float* __restrict__ aux2_b,
    const float* __restrict__ final_W, const float* __restrict__ final_b,
    float* __restrict__ fbuf, float* __restrict__ stf,
    float* __restrict__ out)
{
    __shared__ float wred[4][12];
    const int tid = threadIdx.x;
    const int r = blockIdx.x * 256 + tid;
    const float invB = 1.0f / BATCH;
    float a[6], c[6];
#pragma unroll
    for (int j = 0; j < 6; ++j) {
        float s = st3[j], q = st3[6 + j];
        float mu = s * invB, var = q * invB - mu * mu;
        float rstd = rsqrtf(var + EPSV);
        a[j] = rstd * bn_gamma[504 + j];
        c[j] = bn_beta[504 + j] - mu * a[j];
    }
    float h[6];
    {
        f32x2 z01 = *(const f32x2*)(z3 + (size_t)r * 6);
        f32x2 z23 = *(const f32x2*)(z3 + (size_t)r * 6 + 2);
        f32x2 z45 = *(const f32x2*)(z3 + (size_t)r * 6 + 4);
        h[0] = z01[0] * a[0] + c[0]; h[1] = z01[1] * a[1] + c[1];
        h[2] = z23[0] * a[2] + c[2]; h[3] = z23[1] * a[3] + c[3];
        h[4] = z45[0] * a[4] + c[4]; h[5] = z45[1] * a[5] + c[5];
    }
    float acc = aux1_b[84];
#pragma unroll
    for (int j = 0; j < 6; ++j) acc += h[j] * aux1_W[504 + j];
    out[(size_t)r * 86 + 84] = tanhf(acc) * aux2_W[84] + aux2_b[84];

    float f[6], s6[6], q6[6];
#pragma unroll
    for (int j = 0; j < 6; ++j) {
        float s = final_b[j];
#pragma unroll
        for (int k = 0; k < 6; ++k) s += h[k] * final_W[j * 6 + k];
        f[j] = tanhf(s);
        s6[j] = f[j]; q6[j] = f[j] * f[j];
    }
    {
        f32x2* fr = (f32x2*)(fbuf + (size_t)r * 6);
        fr[0] = (f32x2){f[0], f[1]};
        fr[1] = (f32x2){f[2], f[3]};
        fr[2] = (f32x2){f[4], f[5]};
    }
#pragma unroll
    for (int off = 32; off >= 1; off >>= 1) {
#pragma unroll
        for (int j = 0; j < 6; ++j) {
            s6[j] += __shfl_xor(s6[j], off, 64);
            q6[j] += __shfl_xor(q6[j], off, 64);
        }
    }
    const int wv = tid >> 6, ln = tid & 63;
    if (ln == 0) {
#pragma unroll
        for (int j = 0; j < 6; ++j) { wred[wv][j] = s6[j]; wred[wv][6 + j] = q6[j]; }
    }
    __syncthreads();
    if (tid < 12) {
        float s = wred[0][tid] + wred[1][tid] + wred[2][tid] + wred[3][tid];
        atomicAdd(&stf[tid], s);
    }
}

// ---------------------------------------------------------------------------
// final_p2: 16 blocks x 256 thr, 1 row/thread.
// ---------------------------------------------------------------------------
__global__ __launch_bounds__(256) void final_p2(
    const float* __restrict__ fbuf, const float* __restrict__ stf,
    const float* __restrict__ fbn_gamma, const float* __restrict__ fbn_beta,
    const float* __restrict__ faux_W, const float* __restrict__ faux_b,
    const float* __restrict__ fout_W, const float* __restrict__ fout_b,
    float* __restrict__ out)
{
    const int tid = threadIdx.x;
    const int r = blockIdx.x * 256 + tid;
    const float invB = 1.0f / BATCH;
    float av[6], cv[6];
#pragma unroll
    for (int j = 0; j < 6; ++j) {
        float mu = stf[j] * invB, var = stf[6 + j] * invB - mu * mu;
        float rstd = rsqrtf(var + EPSV);
        av[j] = rstd * fbn_gamma[j];
        cv[j] = fbn_beta[j] - mu * av[j];
    }
    float f[6];
    {
        f32x2 f01 = *(const f32x2*)(fbuf + (size_t)r * 6);
        f32x2 f23 = *(const f32x2*)(fbuf + (size_t)r * 6 + 2);
        f32x2 f45 = *(const f32x2*)(fbuf + (size_t)r * 6 + 4);
        f[0] = f01[0]; f[1] = f01[1]; f[2] = f23[0];
        f[3] = f23[1]; f[4] = f45[0]; f[5] = f45[1];
    }
    float acc2 = faux_b[0];
#pragma unroll
    for (int j = 0; j < 6; ++j) acc2 += (f[j] * av[j] + cv[j]) * faux_W[j];
    float fa  = tanhf(acc2);
    float pre = fa * fout_W[0] + fout_b[0];
    out[(size_t)r * 86 + 85] = 1.0f / (1.0f + expf(-pre));
}

// ---------------------------------------------------------------------------
extern "C" void kernel_launch(void* const* d_in, const int* in_sizes, int n_in,
                              void* d_out, int out_size, void* d_ws, size_t ws_size,
                              hipStream_t stream)
{
    const float* x      = (const float*)d_in[0];
    const float* gene_W = (const float*)d_in[1];
    const float* gene_b = (const float*)d_in[2];
    const float* term_W = (const float*)d_in[3];
    const float* term_b = (const float*)d_in[4];
    const float* bn_g   = (const float*)d_in[5];
    const float* bn_b   = (const float*)d_in[6];
    const float* a1W    = (const float*)d_in[7];
    const float* a1b    = (const float*)d_in[8];
    const float* a2W    = (const float*)d_in[9];
    const float* a2b    = (const float*)d_in[10];
    const float* fW     = (const float*)d_in[11];
    const float* fb     = (const float*)d_in[12];
    const float* fbn_g  = (const float*)d_in[13];
    const float* fbn_b  = (const float*)d_in[14];
    const float* fxW    = (const float*)d_in[15];
    const float* fxb    = (const float*)d_in[16];
    const float* foW    = (const float*)d_in[17];
    const float* fob    = (const float*)d_in[18];
    float* out = (float*)d_out;

    const size_t M0B = (size_t)NF0 * GDIM * 2;            // 3,145,728
    const size_t PB  = (size_t)NSPLIT * BATCH * NF0 * 2;  // 25,165,824
    const size_t Z0B = (size_t)BATCH * NF0 * 4;           // 6,291,456

    char* ws = (char*)d_ws;
    uint16_t* m0b  = (uint16_t*)ws;
    uint16_t* pbuf = (uint16_t*)(ws + M0B);
    float*    z0   = (float*)(ws + M0B + PB);
    float*    z1   = (float*)(ws + M0B + PB + Z0B);
    float*    z2   = (float*)(ws + M0B + PB + Z0B + 1572864);
    float*    z3   = (float*)(ws + M0B + PB + Z0B + 1572864 + 393216);
    float*    stats = (float*)(ws + M0B + PB + Z0B + 1572864 + 393216 + 98304);
    float* st0 = stats;          // 384+384
    float* st1 = stats + 768;    // 96+96
    float* st2 = stats + 960;    // 24+24
    float* st3 = stats + 1008;   // 6+6
    float* stf = stats + 1020;   // 6+6 (final-BN stats; zeroed by prep)
    float* bias0 = stats + 1040; // 384 (written by prep block 0)
    float* fbuf  = stats + 2048; // 4096*6 f32

    prep_kernel<<<1024, 256, 0, stream>>>(gene_W, term_W, term_b, gene_b,
                                          m0b, stats);
    gemm_wide<<<dim3(32, NSPLIT), 512, 0, stream>>>(x, m0b, pbuf, GDIM / NSPLIT);
    lzero_kernel<<<512, 256, 0, stream>>>(pbuf, bias0, z0, st0);
    level_kernel<16, 16, 64, 0><<<256, 256, 0, stream>>>(
        z0, z1, st0, st1, term_W, term_b, bn_g, bn_b, a1W, a1b, a2W, a2b, out);
    level_kernel<4, 64, 80, 64><<<64, 256, 0, stream>>>(
        z1, z2, st1, st2, term_W, term_b, bn_g, bn_b, a1W, a1b, a2W, a2b, out);
    level_kernel<1, 256, 84, 80><<<16, 256, 0, stream>>>(
        z2, z3, st2, st3, term_W, term_b, bn_g, bn_b, a1W, a1b, a2W, a2b, out);
    final_p1<<<16, 256, 0, stream>>>(
        z3, st3, bn_g, bn_b, a1W, a1b, a2W, a2b, fW, fb, fbuf, stf, out);
    final_p2<<<16, 256, 0, stream>>>(
        fbuf, stf, fbn_g, fbn_b, fxW, fxb, foW, fob, out);
}